// Round 1
// baseline (1043.867 us; speedup 1.0000x reference)
//
#include <hip/hip_runtime.h>
#include <math.h>

#define MTOT 9216      // 96*96 pixels (both query and support)
#define CDIM 256
#define KSEL 20
#define NEGV (-1e30f)
#define NCHUNK 8
#define CHUNKM 1152    // columns per chunk (MTOT / NCHUNK)
#define BN 64          // rows per block
#define BM 64          // cols per tile
#define KC 64          // K staging depth
#define NTILES (CHUNKM / BM)   // 18

// Sorted-ascending top-K insert; l[0] is the current K-th largest.
// Fully unrolled -> static register indexing (no scratch).
__device__ __forceinline__ void insert_sorted(float (&l)[KSEL], float v) {
    if (v > l[0]) {
#pragma unroll
        for (int i = 0; i < KSEL - 1; ++i) {
            float nxt = l[i + 1];
            l[i] = fminf(nxt, v);
            v = fmaxf(nxt, v);
        }
        l[KSEL - 1] = v;
    }
}

// Kernel 1: per-pixel inverse L2 norms + fg mask
__global__ __launch_bounds__(256) void prep_kernel(
    const int* __restrict__ ql, const int* __restrict__ color,
    const float* __restrict__ qf, const float* __restrict__ sf,
    float* __restrict__ invq, float* __restrict__ invs, int* __restrict__ mask)
{
    int m = blockIdx.x * blockDim.x + threadIdx.x;
    if (m >= MTOT) return;
    float sq = 0.f, ss = 0.f;
#pragma unroll 8
    for (int c = 0; c < CDIM; ++c) {
        float a = qf[(size_t)c * MTOT + m];
        float b = sf[(size_t)c * MTOT + m];
        sq += a * a;
        ss += b * b;
    }
    invq[m] = 1.0f / fmaxf(sqrtf(sq), 1e-12f);
    invs[m] = 1.0f / fmaxf(sqrtf(ss), 1e-12f);
    int c0 = color[0], c1 = color[1], c2 = color[2];
    mask[m] = (ql[3 * m] == c0 && ql[3 * m + 1] == c1 && ql[3 * m + 2] == c2) ? 1 : 0;
}

// Kernel 2: fused sim-tile GEMM + streaming per-row top-20 (fg/bg) per chunk
__global__ __launch_bounds__(256) void matchsim_kernel(
    const float* __restrict__ qf, const float* __restrict__ sf,
    const float* __restrict__ invq, const float* __restrict__ invs,
    const int* __restrict__ mask, float* __restrict__ part)
{
    __shared__ float lds[4096 + 4096 + BN * 65];   // Stile | Qtile | simt(padded)
    float* Stile = lds;
    float* Qtile = lds + 4096;
    float* simt  = lds + 8192;

    const int t = threadIdx.x;
    const int rowblk = blockIdx.x / NCHUNK;
    const int chunk  = blockIdx.x - rowblk * NCHUNK;
    const int r0 = rowblk * BN;
    const int mbase = chunk * CHUNKM;
    const int tx = t & 15, ty = t >> 4;

    float fgl[KSEL], bgl[KSEL];
#pragma unroll
    for (int i = 0; i < KSEL; ++i) { fgl[i] = NEGV; bgl[i] = NEGV; }

    const float4 isv = *reinterpret_cast<const float4*>(&invs[r0 + 4 * ty]);

    const int selr  = t & 63;   // selection: 4 threads per row, 16 cols each
    const int selcg = t >> 6;

    for (int tile = 0; tile < NTILES; ++tile) {
        const int m0 = mbase + tile * BM;
        float acc[4][4];
#pragma unroll
        for (int i = 0; i < 4; ++i)
#pragma unroll
            for (int j = 0; j < 4; ++j) acc[i][j] = 0.f;

        for (int kc0 = 0; kc0 < CDIM; kc0 += KC) {
            __syncthreads();   // protects LDS from previous phase readers
#pragma unroll
            for (int i = 0; i < 4; ++i) {
                int f = t + i * 256;          // float4 index within 64x64 tile
                int kc = f >> 4;              // 16 float4 per K-row
                int off = (f & 15) << 2;
                float4 sv = *reinterpret_cast<const float4*>(&sf[(size_t)(kc0 + kc) * MTOT + r0 + off]);
                float4 qv = *reinterpret_cast<const float4*>(&qf[(size_t)(kc0 + kc) * MTOT + m0 + off]);
                *reinterpret_cast<float4*>(&Stile[kc * 64 + off]) = sv;
                *reinterpret_cast<float4*>(&Qtile[kc * 64 + off]) = qv;
            }
            __syncthreads();
#pragma unroll 8
            for (int kc = 0; kc < KC; ++kc) {
                float4 sv = *reinterpret_cast<const float4*>(&Stile[kc * 64 + 4 * ty]);
                float4 qv = *reinterpret_cast<const float4*>(&Qtile[kc * 64 + 4 * tx]);
                acc[0][0] += sv.x * qv.x; acc[0][1] += sv.x * qv.y;
                acc[0][2] += sv.x * qv.z; acc[0][3] += sv.x * qv.w;
                acc[1][0] += sv.y * qv.x; acc[1][1] += sv.y * qv.y;
                acc[1][2] += sv.y * qv.z; acc[1][3] += sv.y * qv.w;
                acc[2][0] += sv.z * qv.x; acc[2][1] += sv.z * qv.y;
                acc[2][2] += sv.z * qv.z; acc[2][3] += sv.z * qv.w;
                acc[3][0] += sv.w * qv.x; acc[3][1] += sv.w * qv.y;
                acc[3][2] += sv.w * qv.z; acc[3][3] += sv.w * qv.w;
            }
        }
        // scale by inverse norms and write sim tile (padded stride 65)
        const float4 iqv = *reinterpret_cast<const float4*>(&invq[m0 + 4 * tx]);
#pragma unroll
        for (int i = 0; i < 4; ++i) {
            float isc = (i == 0) ? isv.x : (i == 1) ? isv.y : (i == 2) ? isv.z : isv.w;
#pragma unroll
            for (int j = 0; j < 4; ++j) {
                float jq = (j == 0) ? iqv.x : (j == 1) ? iqv.y : (j == 2) ? iqv.z : iqv.w;
                simt[(4 * ty + i) * 65 + 4 * tx + j] = acc[i][j] * isc * jq;
            }
        }
        __syncthreads();
        // streaming selection into private sorted top-20 lists
        const int mstart = m0 + selcg * 16;
#pragma unroll
        for (int c = 0; c < 16; ++c) {
            float v = simt[selr * 65 + selcg * 16 + c];
            if (mask[mstart + c]) insert_sorted(fgl, v);
            else                  insert_sorted(bgl, v);
        }
    }

    // merge the 4 per-row private lists -> one top-20 per row per class
    __syncthreads();
    // FG
#pragma unroll
    for (int k = 0; k < KSEL; ++k) lds[t * KSEL + k] = fgl[k];
    __syncthreads();
    if (t < BN) {
        float outl[KSEL];
#pragma unroll
        for (int i = 0; i < KSEL; ++i) outl[i] = NEGV;
        for (int g = 0; g < 4; ++g) {
            const float* src = &lds[(t + BN * g) * KSEL];
            for (int k = 0; k < KSEL; ++k) insert_sorted(outl, src[k]);
        }
        float* dst = &part[((size_t)(r0 + t) * NCHUNK + chunk) * (2 * KSEL)];
#pragma unroll
        for (int k = 0; k < KSEL; ++k) dst[k] = outl[k];
    }
    __syncthreads();
    // BG
#pragma unroll
    for (int k = 0; k < KSEL; ++k) lds[t * KSEL + k] = bgl[k];
    __syncthreads();
    if (t < BN) {
        float outl[KSEL];
#pragma unroll
        for (int i = 0; i < KSEL; ++i) outl[i] = NEGV;
        for (int g = 0; g < 4; ++g) {
            const float* src = &lds[(t + BN * g) * KSEL];
            for (int k = 0; k < KSEL; ++k) insert_sorted(outl, src[k]);
        }
        float* dst = &part[((size_t)(r0 + t) * NCHUNK + chunk) * (2 * KSEL)] + KSEL;
#pragma unroll
        for (int k = 0; k < KSEL; ++k) dst[k] = outl[k];
    }
}

// Kernel 3: merge 8 chunk-lists per row per class -> mean of top-20
__global__ __launch_bounds__(256) void finalize_kernel(
    const float* __restrict__ part, float* __restrict__ out)
{
    int n = blockIdx.x * blockDim.x + threadIdx.x;
    if (n >= MTOT) return;
    const float* base = &part[(size_t)n * NCHUNK * 2 * KSEL];

    float l[KSEL];
#pragma unroll
    for (int i = 0; i < KSEL; ++i) l[i] = NEGV;
    for (int ch = 0; ch < NCHUNK; ++ch) {
        const float* src = base + ch * (2 * KSEL);
        for (int k = 0; k < KSEL; ++k) insert_sorted(l, src[k]);
    }
    float sm = 0.f;
#pragma unroll
    for (int k = 0; k < KSEL; ++k) sm += l[k];
    out[n] = sm * (1.0f / KSEL);

#pragma unroll
    for (int i = 0; i < KSEL; ++i) l[i] = NEGV;
    for (int ch = 0; ch < NCHUNK; ++ch) {
        const float* src = base + ch * (2 * KSEL) + KSEL;
        for (int k = 0; k < KSEL; ++k) insert_sorted(l, src[k]);
    }
    sm = 0.f;
#pragma unroll
    for (int k = 0; k < KSEL; ++k) sm += l[k];
    out[MTOT + n] = sm * (1.0f / KSEL);
}

extern "C" void kernel_launch(void* const* d_in, const int* in_sizes, int n_in,
                              void* d_out, int out_size, void* d_ws, size_t ws_size,
                              hipStream_t stream) {
    const int*   ql    = (const int*)d_in[0];
    const int*   color = (const int*)d_in[1];
    const float* qf    = (const float*)d_in[2];
    const float* sf    = (const float*)d_in[3];
    float* out = (float*)d_out;

    // ws layout: invq[9216] f32 | invs[9216] f32 | mask[9216] i32 | part[9216*8*2*20] f32
    float* invq = (float*)d_ws;
    float* invs = invq + MTOT;
    int*   mask = (int*)(invs + MTOT);
    float* part = (float*)(mask + MTOT);

    prep_kernel<<<(MTOT + 255) / 256, 256, 0, stream>>>(ql, color, qf, sf, invq, invs, mask);
    matchsim_kernel<<<(MTOT / BN) * NCHUNK, 256, 0, stream>>>(qf, sf, invq, invs, mask, part);
    finalize_kernel<<<(MTOT + 255) / 256, 256, 0, stream>>>(part, out);
}

// Round 2
// 305.891 us; speedup vs baseline: 3.4125x; 3.4125x over previous
//
#include <hip/hip_runtime.h>
#include <math.h>

#define MTOT 9216      // 96*96 pixels
#define CDIM 256
#define KSEL 20
#define NEGV (-1e30f)
#define NCHUNK 8
#define CHUNKM 1152
#define BN 32          // rows (support pixels) per block
#define BM 128         // cols (query pixels) per tile
#define NTILES 9       // CHUNKM / BM

typedef __attribute__((ext_vector_type(8))) short short8;
typedef __attribute__((ext_vector_type(8))) unsigned short ushort8;
typedef __attribute__((ext_vector_type(4))) float f32x4;

__device__ __forceinline__ unsigned short f2bf(float v) {
    unsigned u = __float_as_uint(v);
    u += 0x7FFF + ((u >> 16) & 1);          // round-to-nearest-even
    return (unsigned short)(u >> 16);
}

// sorted-ascending top-K list; l[0] = current K-th largest
__device__ __forceinline__ void ins20(float (&l)[KSEL], float v) {
#pragma unroll
    for (int i = 0; i < KSEL - 1; ++i) {
        float nxt = l[i + 1];
        l[i] = fminf(nxt, v);
        v = fmaxf(nxt, v);
    }
    l[KSEL - 1] = v;
}
__device__ __forceinline__ void ins20g(float (&l)[KSEL], float v) {
    if (v > l[0]) ins20(l, v);
}

// Kernel 1: inverse L2 norms + fg mask + class-sorted column slots
__global__ __launch_bounds__(256) void prep_kernel(
    const int* __restrict__ ql, const int* __restrict__ color,
    const float* __restrict__ qf, const float* __restrict__ sf,
    float* __restrict__ invq, float* __restrict__ invs,
    int* __restrict__ slot, int* __restrict__ cnt)
{
    int m = blockIdx.x * 256 + threadIdx.x;
    if (m >= MTOT) return;
    float sq = 0.f, ss = 0.f;
#pragma unroll 8
    for (int c = 0; c < CDIM; ++c) {
        float a = qf[c * MTOT + m];
        float b = sf[c * MTOT + m];
        sq += a * a; ss += b * b;
    }
    invq[m] = 1.0f / fmaxf(sqrtf(sq), 1e-12f);
    invs[m] = 1.0f / fmaxf(sqrtf(ss), 1e-12f);
    bool fg = (ql[3*m] == color[0]) & (ql[3*m+1] == color[1]) & (ql[3*m+2] == color[2]);
    int s = fg ? atomicAdd(&cnt[0], 1) : (MTOT - 1 - atomicAdd(&cnt[1], 1));
    slot[m] = s;
}

// Kernel 2: normalize, cast bf16, transpose [C][M] -> [m][C] (q permuted by slot)
__global__ __launch_bounds__(256) void convert_kernel(
    const float* __restrict__ qf, const float* __restrict__ sf,
    const float* __restrict__ invq, const float* __restrict__ invs,
    const int* __restrict__ slot,
    unsigned short* __restrict__ qbt, unsigned short* __restrict__ sbt)
{
    __shared__ unsigned short tile[32 * 264];   // 32 m-rows x 256 c, pad 264
    int bid = blockIdx.x;
    bool isQ = bid < (MTOT / 32);
    int m0 = (isQ ? bid : bid - MTOT / 32) * 32;
    const float* src = isQ ? qf : sf;
    const float* inv = isQ ? invq : invs;
    int t = threadIdx.x;
    int ml = t & 31, c0 = (t >> 5) * 32;
    float iv = inv[m0 + ml];
#pragma unroll 8
    for (int i = 0; i < 32; ++i) {
        int c = c0 + i;
        tile[ml * 264 + c] = f2bf(src[c * MTOT + m0 + ml] * iv);
    }
    __syncthreads();
    int row = t >> 3, ch = t & 7;
    int drow = isQ ? slot[m0 + row] : (m0 + row);
    unsigned short* dst = (isQ ? qbt : sbt) + (size_t)drow * 256 + ch * 32;
#pragma unroll
    for (int j = 0; j < 4; ++j)
        *reinterpret_cast<ushort8*>(dst + j * 8) =
            *reinterpret_cast<const ushort8*>(&tile[row * 264 + ch * 32 + j * 8]);
}

// Kernel 3: MFMA sim tiles + streaming per-row top-20 (fg/bg) per chunk
__global__ __launch_bounds__(256, 3) void matchsim_kernel(
    const unsigned short* __restrict__ qbt, const unsigned short* __restrict__ sbt,
    const int* __restrict__ cnt, float* __restrict__ part)
{
    // layout: Sb[32][256] bf16 swz @0 (16K) | Qb[128][64] bf16 swz @16K (16K) |
    //         simt[32][133] f32 @32768 (17024) ; merge aliases @0: mgF 256x21, mgB @21504
    __shared__ __align__(16) char smem[49792];
    char* Qb = smem + 16384;
    float* simt = (float*)(smem + 32768);
    float* mgF = (float*)smem;
    float* mgB = (float*)(smem + 21504);

    const int t = threadIdx.x;
    const int w = t >> 6, l = t & 63;
    const int rowblk = blockIdx.x >> 3;
    const int chunk = blockIdx.x & 7;
    const int r0 = rowblk * BN;
    const int mbase = chunk * CHUNKM;
    const int fgc = cnt[0];

    // stage Sb: full K resident, swizzled rows (512 B each)
    {
        int row = t >> 3, cb = t & 7;
        const ushort8* gs = (const ushort8*)(sbt + (size_t)(r0 + row) * 256);
#pragma unroll
        for (int i = 0; i < 4; ++i) {
            int ch = cb + i * 8;
            ushort8 v = gs[ch];
            int byte = (row * 512 + ch * 16) ^ ((row & 7) << 4);
            *(ushort8*)(smem + byte) = v;
        }
    }

    float fgl[KSEL], bgl[KSEL];
#pragma unroll
    for (int i = 0; i < KSEL; ++i) { fgl[i] = NEGV; bgl[i] = NEGV; }

    // Q register prefetch (64 B / thread / kc-slab)
    ushort8 qr[4];
    const int qml = t >> 3, qch = t & 7;
    auto loadQ = [&](int tt, int kk) {
        const unsigned short* base = qbt + (size_t)(mbase + tt * BM) * 256 + kk * 64 + qch * 8;
#pragma unroll
        for (int i = 0; i < 4; ++i)
            qr[i] = *(const ushort8*)(base + (size_t)(qml + 32 * i) * 256);
    };
    loadQ(0, 0);

    // fragment read addressing (byte offsets + XOR swizzle)
    const int arow = l & 15;
    const int aswz = (arow & 7) << 4;
    const int abase0 = arow * 512;
    const int abase1 = (arow + 16) * 512;
    const int kofs = (l >> 4) * 16;                 // k-group byte offset
    const int bcol0 = w * 32 + (l & 15);
    const int bcol1 = bcol0 + 16;
    const int bbyte0 = bcol0 * 128, bswz0 = (bcol0 & 7) << 4;
    const int bbyte1 = bcol1 * 128, bswz1 = (bcol1 & 7) << 4;

    for (int tile = 0; tile < NTILES; ++tile) {
        f32x4 acc00 = {0,0,0,0}, acc01 = {0,0,0,0}, acc10 = {0,0,0,0}, acc11 = {0,0,0,0};
        for (int kcb = 0; kcb < 4; ++kcb) {
            if (tile | kcb) __syncthreads();        // prior Qb readers / selection done
#pragma unroll
            for (int i = 0; i < 4; ++i) {           // write Qb slab
                int mlr = qml + 32 * i;
                int byte = (mlr * 128 + qch * 16) ^ ((mlr & 7) << 4);
                *(ushort8*)(Qb + byte) = qr[i];
            }
            int nk = kcb + 1, nt = tile;
            if (nk == 4) { nk = 0; ++nt; }
            if (nt < NTILES) loadQ(nt, nk);         // prefetch next slab
            __syncthreads();
#pragma unroll
            for (int ks = 0; ks < 2; ++ks) {
                int kb = kcb * 128 + ks * 64 + kofs;
                short8 a0 = *(const short8*)(smem + ((abase0 + kb) ^ aswz));
                short8 a1 = *(const short8*)(smem + ((abase1 + kb) ^ aswz));
                int klb = ks * 64 + kofs;
                short8 b0 = *(const short8*)(Qb + ((bbyte0 + klb) ^ bswz0));
                short8 b1 = *(const short8*)(Qb + ((bbyte1 + klb) ^ bswz1));
                acc00 = __builtin_amdgcn_mfma_f32_16x16x32_bf16(a0, b0, acc00, 0, 0, 0);
                acc01 = __builtin_amdgcn_mfma_f32_16x16x32_bf16(a0, b1, acc01, 0, 0, 0);
                acc10 = __builtin_amdgcn_mfma_f32_16x16x32_bf16(a1, b0, acc10, 0, 0, 0);
                acc11 = __builtin_amdgcn_mfma_f32_16x16x32_bf16(a1, b1, acc11, 0, 0, 0);
            }
        }
        // accumulators -> simt (row = S-pixel, col = Q-pixel)
        {
            int rbase = (l >> 4) * 4;
            int c0 = w * 32 + (l & 15);
#pragma unroll
            for (int r = 0; r < 4; ++r) {
                simt[(rbase + r) * 133 + c0]           = acc00[r];
                simt[(rbase + r) * 133 + c0 + 16]      = acc01[r];
                simt[(rbase + r + 16) * 133 + c0]      = acc10[r];
                simt[(rbase + r + 16) * 133 + c0 + 16] = acc11[r];
            }
        }
        __syncthreads();
        // streaming selection (columns class-sorted -> uniform branches)
        {
            int row = t & 31, cb = (t >> 5) * 16;
            int mabs = mbase + tile * BM + cb;
            const float* sr = &simt[row * 133 + cb];
#pragma unroll
            for (int c = 0; c < 16; ++c) {
                float v = sr[c];
                if (mabs + c < fgc) ins20g(fgl, v);
                else                ins20g(bgl, v);
            }
        }
    }

    __syncthreads();
    // dump lists (stride 21 -> conflict-free)
#pragma unroll
    for (int k = 0; k < KSEL; ++k) { mgF[t * 21 + k] = fgl[k]; mgB[t * 21 + k] = bgl[k]; }
    __syncthreads();
    // merge tree 8 -> 4 (all 256 threads: 128 fg + 128 bg workers)
    {
        int cls = t >> 7, u = t & 127;
        float* buf = cls ? mgB : mgF;
        int row = u & 31, p = u >> 5;
        int sa = row + 64 * p, sb = sa + 32;
        float la[KSEL];
#pragma unroll
        for (int k = 0; k < KSEL; ++k) la[k] = buf[sa * 21 + k];
        const float* sp = &buf[sb * 21];
        for (int j = KSEL - 1; j >= 0; --j) { float v = sp[j]; if (v <= la[0]) break; ins20(la, v); }
#pragma unroll
        for (int k = 0; k < KSEL; ++k) buf[sa * 21 + k] = la[k];
    }
    __syncthreads();
    // 4 -> 2
    {
        int cls = t >> 7, u = t & 127;
        if (u < 64) {
            float* buf = cls ? mgB : mgF;
            int row = u & 31, p = u >> 5;
            int sa = row + 128 * p, sb = sa + 64;
            float la[KSEL];
#pragma unroll
            for (int k = 0; k < KSEL; ++k) la[k] = buf[sa * 21 + k];
            const float* sp = &buf[sb * 21];
            for (int j = KSEL - 1; j >= 0; --j) { float v = sp[j]; if (v <= la[0]) break; ins20(la, v); }
#pragma unroll
            for (int k = 0; k < KSEL; ++k) buf[sa * 21 + k] = la[k];
        }
    }
    __syncthreads();
    // 2 -> 1, write part
    {
        int cls = t >> 7, u = t & 127;
        if (u < 32) {
            float* buf = cls ? mgB : mgF;
            int row = u;
            float la[KSEL];
#pragma unroll
            for (int k = 0; k < KSEL; ++k) la[k] = buf[row * 21 + k];
            const float* sp = &buf[(row + 128) * 21];
            for (int j = KSEL - 1; j >= 0; --j) { float v = sp[j]; if (v <= la[0]) break; ins20(la, v); }
            float* dst = &part[((size_t)(r0 + row) * NCHUNK + chunk) * (2 * KSEL) + cls * KSEL];
#pragma unroll
            for (int k = 0; k < KSEL; ++k) dst[k] = la[k];
        }
    }
}

// Kernel 4: merge 8 chunk-lists per row per class -> mean
__global__ __launch_bounds__(256) void finalize_kernel(
    const float* __restrict__ part, float* __restrict__ out)
{
    int n = blockIdx.x * 256 + threadIdx.x;
    if (n >= MTOT) return;
    const float* base = part + (size_t)n * NCHUNK * 2 * KSEL;
#pragma unroll
    for (int cls = 0; cls < 2; ++cls) {
        float la[KSEL];
        const float* c0 = base + cls * KSEL;
#pragma unroll
        for (int k = 0; k < KSEL; ++k) la[k] = c0[k];
        for (int ch = 1; ch < NCHUNK; ++ch) {
            const float* sp = base + ch * 2 * KSEL + cls * KSEL;
            for (int j = KSEL - 1; j >= 0; --j) { float v = sp[j]; if (v <= la[0]) break; ins20(la, v); }
        }
        float s = 0.f;
#pragma unroll
        for (int k = 0; k < KSEL; ++k) s += la[k];
        out[cls * MTOT + n] = s * (1.0f / KSEL);
    }
}

extern "C" void kernel_launch(void* const* d_in, const int* in_sizes, int n_in,
                              void* d_out, int out_size, void* d_ws, size_t ws_size,
                              hipStream_t stream) {
    const int*   ql    = (const int*)d_in[0];
    const int*   color = (const int*)d_in[1];
    const float* qf    = (const float*)d_in[2];
    const float* sf    = (const float*)d_in[3];
    float* out = (float*)d_out;

    // ws: invq | invs | slot | cnt[4] | qbt bf16 | sbt bf16 | part   (~21.4 MB)
    float* invq = (float*)d_ws;
    float* invs = invq + MTOT;
    int*   slot = (int*)(invs + MTOT);
    int*   cnt  = slot + MTOT;
    unsigned short* qbt = (unsigned short*)(cnt + 4);
    unsigned short* sbt = qbt + (size_t)MTOT * CDIM;
    float* part = (float*)(sbt + (size_t)MTOT * CDIM);

    hipMemsetAsync(cnt, 0, 16, stream);
    prep_kernel<<<MTOT / 256, 256, 0, stream>>>(ql, color, qf, sf, invq, invs, slot, cnt);
    convert_kernel<<<2 * (MTOT / 32), 256, 0, stream>>>(qf, sf, invq, invs, slot, qbt, sbt);
    matchsim_kernel<<<(MTOT / BN) * NCHUNK, 256, 0, stream>>>(qbt, sbt, cnt, part);
    finalize_kernel<<<MTOT / 256, 256, 0, stream>>>(part, out);
}

// Round 3
// 253.048 us; speedup vs baseline: 4.1252x; 1.2088x over previous
//
#include <hip/hip_runtime.h>
#include <math.h>

#define MTOT 9216      // 96*96 pixels
#define CDIM 256
#define KSEL 20
#define NEGV (-1e30f)
#define NCHUNK 8
#define CHUNKM 1152
#define BN 32          // rows (support pixels) per block
#define BM 128         // cols (query pixels) per tile
#define NTILES 9       // CHUNKM / BM
#define SSTR 136       // simt row stride (floats): 16B-aligned, 2-way-max banks

typedef __attribute__((ext_vector_type(8))) short short8;
typedef __attribute__((ext_vector_type(8))) unsigned short ushort8;
typedef __attribute__((ext_vector_type(4))) float f32x4;

__device__ __forceinline__ unsigned short f2bf(float v) {
    unsigned u = __float_as_uint(v);
    u += 0x7FFF + ((u >> 16) & 1);          // round-to-nearest-even
    return (unsigned short)(u >> 16);
}

// sorted-ascending top-K; l[0] = current K-th largest.
// Unconditional branchless insert: inserting any v <= l[0] (incl. NEGV mask)
// is a provable no-op because v is clamped to l[0] first.
__device__ __forceinline__ void ins20u(float (&l)[KSEL], float v) {
    v = fmaxf(v, l[0]);
#pragma unroll
    for (int i = 0; i < KSEL - 1; ++i) {
        float nxt = l[i + 1];
        l[i] = fminf(nxt, v);
        v = fmaxf(nxt, v);
    }
    l[KSEL - 1] = v;
}
// guarded variant for merge phases (rare-insert regime)
__device__ __forceinline__ void ins20(float (&l)[KSEL], float v) {
#pragma unroll
    for (int i = 0; i < KSEL - 1; ++i) {
        float nxt = l[i + 1];
        l[i] = fminf(nxt, v);
        v = fmaxf(nxt, v);
    }
    l[KSEL - 1] = v;
}

// Kernel 1: inverse L2 norms + fg mask + class-sorted column slots
__global__ __launch_bounds__(256) void prep_kernel(
    const int* __restrict__ ql, const int* __restrict__ color,
    const float* __restrict__ qf, const float* __restrict__ sf,
    float* __restrict__ invq, float* __restrict__ invs,
    int* __restrict__ slot, int* __restrict__ cnt)
{
    int m = blockIdx.x * 256 + threadIdx.x;
    if (m >= MTOT) return;
    float sq = 0.f, ss = 0.f;
#pragma unroll 8
    for (int c = 0; c < CDIM; ++c) {
        float a = qf[c * MTOT + m];
        float b = sf[c * MTOT + m];
        sq += a * a; ss += b * b;
    }
    invq[m] = 1.0f / fmaxf(sqrtf(sq), 1e-12f);
    invs[m] = 1.0f / fmaxf(sqrtf(ss), 1e-12f);
    bool fg = (ql[3*m] == color[0]) & (ql[3*m+1] == color[1]) & (ql[3*m+2] == color[2]);
    int s = fg ? atomicAdd(&cnt[0], 1) : (MTOT - 1 - atomicAdd(&cnt[1], 1));
    slot[m] = s;
}

// Kernel 2: normalize, cast bf16, transpose [C][M] -> [m][C] (q permuted by slot)
__global__ __launch_bounds__(256) void convert_kernel(
    const float* __restrict__ qf, const float* __restrict__ sf,
    const float* __restrict__ invq, const float* __restrict__ invs,
    const int* __restrict__ slot,
    unsigned short* __restrict__ qbt, unsigned short* __restrict__ sbt)
{
    __shared__ unsigned short tile[32 * 264];
    int bid = blockIdx.x;
    bool isQ = bid < (MTOT / 32);
    int m0 = (isQ ? bid : bid - MTOT / 32) * 32;
    const float* src = isQ ? qf : sf;
    const float* inv = isQ ? invq : invs;
    int t = threadIdx.x;
    int ml = t & 31, c0 = (t >> 5) * 32;
    float iv = inv[m0 + ml];
#pragma unroll 8
    for (int i = 0; i < 32; ++i) {
        int c = c0 + i;
        tile[ml * 264 + c] = f2bf(src[c * MTOT + m0 + ml] * iv);
    }
    __syncthreads();
    int row = t >> 3, ch = t & 7;
    int drow = isQ ? slot[m0 + row] : (m0 + row);
    unsigned short* dst = (isQ ? qbt : sbt) + (size_t)drow * 256 + ch * 32;
#pragma unroll
    for (int j = 0; j < 4; ++j)
        *reinterpret_cast<ushort8*>(dst + j * 8) =
            *reinterpret_cast<const ushort8*>(&tile[row * 264 + ch * 32 + j * 8]);
}

// Kernel 3: MFMA sim tiles + streaming per-row top-20 (fg/bg) per chunk
__global__ __launch_bounds__(256, 3) void matchsim_kernel(
    const unsigned short* __restrict__ qbt, const unsigned short* __restrict__ sbt,
    const int* __restrict__ cnt, float* __restrict__ part)
{
    // layout: Sb[32][256] bf16 swz @0 (16K) | Qb[128][64] bf16 swz @16K (16K) |
    //         simt[32][SSTR] f32 @32768 ; merge aliases @0: mgF 256x21, mgB @21504
    __shared__ __align__(16) char smem[32768 + 32 * SSTR * 4];
    char* Qb = smem + 16384;
    float* simt = (float*)(smem + 32768);
    float* mgF = (float*)smem;
    float* mgB = (float*)(smem + 21504);

    const int t = threadIdx.x;
    const int w = t >> 6, l = t & 63;
    const int rowblk = blockIdx.x >> 3;
    const int chunk = blockIdx.x & 7;
    const int r0 = rowblk * BN;
    const int mbase = chunk * CHUNKM;
    const int fgc = cnt[0];

    // stage Sb: full K resident, swizzled rows (512 B each)
    {
        int row = t >> 3, cb = t & 7;
        const ushort8* gs = (const ushort8*)(sbt + (size_t)(r0 + row) * 256);
#pragma unroll
        for (int i = 0; i < 4; ++i) {
            int ch = cb + i * 8;
            ushort8 v = gs[ch];
            int byte = (row * 512 + ch * 16) ^ ((row & 7) << 4);
            *(ushort8*)(smem + byte) = v;
        }
    }

    float fgl[KSEL], bgl[KSEL];
#pragma unroll
    for (int i = 0; i < KSEL; ++i) { fgl[i] = NEGV; bgl[i] = NEGV; }

    // Q register prefetch (64 B / thread / kc-slab)
    ushort8 qr[4];
    const int qml = t >> 3, qch = t & 7;
    auto loadQ = [&](int tt, int kk) {
        const unsigned short* base = qbt + (size_t)(mbase + tt * BM) * 256 + kk * 64 + qch * 8;
#pragma unroll
        for (int i = 0; i < 4; ++i)
            qr[i] = *(const ushort8*)(base + (size_t)(qml + 32 * i) * 256);
    };
    loadQ(0, 0);

    // fragment read addressing (byte offsets + XOR swizzle)
    const int arow = l & 15;
    const int aswz = (arow & 7) << 4;
    const int abase0 = arow * 512;
    const int abase1 = (arow + 16) * 512;
    const int kofs = (l >> 4) * 16;
    const int bcol0 = w * 32 + (l & 15);
    const int bcol1 = bcol0 + 16;
    const int bbyte0 = bcol0 * 128, bswz0 = (bcol0 & 7) << 4;
    const int bbyte1 = bcol1 * 128, bswz1 = (bcol1 & 7) << 4;

    for (int tile = 0; tile < NTILES; ++tile) {
        f32x4 acc00 = {0,0,0,0}, acc01 = {0,0,0,0}, acc10 = {0,0,0,0}, acc11 = {0,0,0,0};
        for (int kcb = 0; kcb < 4; ++kcb) {
            if (tile | kcb) __syncthreads();
#pragma unroll
            for (int i = 0; i < 4; ++i) {           // write Qb slab
                int mlr = qml + 32 * i;
                int byte = (mlr * 128 + qch * 16) ^ ((mlr & 7) << 4);
                *(ushort8*)(Qb + byte) = qr[i];
            }
            int nk = kcb + 1, nt = tile;
            if (nk == 4) { nk = 0; ++nt; }
            if (nt < NTILES) loadQ(nt, nk);
            __syncthreads();
#pragma unroll
            for (int ks = 0; ks < 2; ++ks) {
                int kb = kcb * 128 + ks * 64 + kofs;
                short8 a0 = *(const short8*)(smem + ((abase0 + kb) ^ aswz));
                short8 a1 = *(const short8*)(smem + ((abase1 + kb) ^ aswz));
                int klb = ks * 64 + kofs;
                short8 b0 = *(const short8*)(Qb + ((bbyte0 + klb) ^ bswz0));
                short8 b1 = *(const short8*)(Qb + ((bbyte1 + klb) ^ bswz1));
                acc00 = __builtin_amdgcn_mfma_f32_16x16x32_bf16(a0, b0, acc00, 0, 0, 0);
                acc01 = __builtin_amdgcn_mfma_f32_16x16x32_bf16(a0, b1, acc01, 0, 0, 0);
                acc10 = __builtin_amdgcn_mfma_f32_16x16x32_bf16(a1, b0, acc10, 0, 0, 0);
                acc11 = __builtin_amdgcn_mfma_f32_16x16x32_bf16(a1, b1, acc11, 0, 0, 0);
            }
        }
        // accumulators -> simt (row = S-pixel, col = Q-pixel)
        {
            int rbase = (l >> 4) * 4;
            int c0 = w * 32 + (l & 15);
#pragma unroll
            for (int r = 0; r < 4; ++r) {
                simt[(rbase + r) * SSTR + c0]           = acc00[r];
                simt[(rbase + r) * SSTR + c0 + 16]      = acc01[r];
                simt[(rbase + r + 16) * SSTR + c0]      = acc10[r];
                simt[(rbase + r + 16) * SSTR + c0 + 16] = acc11[r];
            }
        }
        __syncthreads();
        // streaming selection: group-uniform class branch, branchless inserts
        {
            int row = t & 31, g = t >> 5;
            int cb = g * 16;
            int mabs = mbase + tile * BM + cb;
            const float* sr = &simt[row * SSTR + cb];
            float4 va = *(const float4*)(sr);
            float4 vb = *(const float4*)(sr + 4);
            float4 vc = *(const float4*)(sr + 8);
            float4 vd = *(const float4*)(sr + 12);
            float v[16] = {va.x, va.y, va.z, va.w, vb.x, vb.y, vb.z, vb.w,
                           vc.x, vc.y, vc.z, vc.w, vd.x, vd.y, vd.z, vd.w};
            if (mabs + 16 <= fgc) {
#pragma unroll
                for (int c = 0; c < 16; ++c) ins20u(fgl, v[c]);
            } else if (mabs >= fgc) {
#pragma unroll
                for (int c = 0; c < 16; ++c) ins20u(bgl, v[c]);
            } else {            // boundary group (at most one wave in the grid)
#pragma unroll
                for (int c = 0; c < 16; ++c) {
                    ins20u(fgl, (mabs + c < fgc) ? v[c] : NEGV);
                    ins20u(bgl, (mabs + c < fgc) ? NEGV : v[c]);
                }
            }
        }
    }

    __syncthreads();
    // dump lists (stride 21 -> conflict-free)
#pragma unroll
    for (int k = 0; k < KSEL; ++k) { mgF[t * 21 + k] = fgl[k]; mgB[t * 21 + k] = bgl[k]; }
    __syncthreads();
    // merge tree 8 -> 4 (all 256 threads: 128 fg + 128 bg workers)
    {
        int cls = t >> 7, u = t & 127;
        float* buf = cls ? mgB : mgF;
        int row = u & 31, p = u >> 5;
        int sa = row + 64 * p, sb = sa + 32;
        float la[KSEL];
#pragma unroll
        for (int k = 0; k < KSEL; ++k) la[k] = buf[sa * 21 + k];
        const float* sp = &buf[sb * 21];
        for (int j = KSEL - 1; j >= 0; --j) { float v = sp[j]; if (v <= la[0]) break; ins20(la, v); }
#pragma unroll
        for (int k = 0; k < KSEL; ++k) buf[sa * 21 + k] = la[k];
    }
    __syncthreads();
    // 4 -> 2
    {
        int cls = t >> 7, u = t & 127;
        if (u < 64) {
            float* buf = cls ? mgB : mgF;
            int row = u & 31, p = u >> 5;
            int sa = row + 128 * p, sb = sa + 64;
            float la[KSEL];
#pragma unroll
            for (int k = 0; k < KSEL; ++k) la[k] = buf[sa * 21 + k];
            const float* sp = &buf[sb * 21];
            for (int j = KSEL - 1; j >= 0; --j) { float v = sp[j]; if (v <= la[0]) break; ins20(la, v); }
#pragma unroll
            for (int k = 0; k < KSEL; ++k) buf[sa * 21 + k] = la[k];
        }
    }
    __syncthreads();
    // 2 -> 1, write part
    {
        int cls = t >> 7, u = t & 127;
        if (u < 32) {
            float* buf = cls ? mgB : mgF;
            int row = u;
            float la[KSEL];
#pragma unroll
            for (int k = 0; k < KSEL; ++k) la[k] = buf[row * 21 + k];
            const float* sp = &buf[(row + 128) * 21];
            for (int j = KSEL - 1; j >= 0; --j) { float v = sp[j]; if (v <= la[0]) break; ins20(la, v); }
            float* dst = &part[((size_t)(r0 + row) * NCHUNK + chunk) * (2 * KSEL) + cls * KSEL];
#pragma unroll
            for (int k = 0; k < KSEL; ++k) dst[k] = la[k];
        }
    }
}

// Kernel 4: merge 8 chunk-lists per row per class -> mean
__global__ __launch_bounds__(256) void finalize_kernel(
    const float* __restrict__ part, float* __restrict__ out)
{
    int n = blockIdx.x * 256 + threadIdx.x;
    if (n >= MTOT) return;
    const float* base = part + (size_t)n * NCHUNK * 2 * KSEL;
#pragma unroll
    for (int cls = 0; cls < 2; ++cls) {
        float la[KSEL];
        const float* c0 = base + cls * KSEL;
#pragma unroll
        for (int k = 0; k < KSEL; ++k) la[k] = c0[k];
        for (int ch = 1; ch < NCHUNK; ++ch) {
            const float* sp = base + ch * 2 * KSEL + cls * KSEL;
            for (int j = KSEL - 1; j >= 0; --j) { float v = sp[j]; if (v <= la[0]) break; ins20(la, v); }
        }
        float s = 0.f;
#pragma unroll
        for (int k = 0; k < KSEL; ++k) s += la[k];
        out[cls * MTOT + n] = s * (1.0f / KSEL);
    }
}

extern "C" void kernel_launch(void* const* d_in, const int* in_sizes, int n_in,
                              void* d_out, int out_size, void* d_ws, size_t ws_size,
                              hipStream_t stream) {
    const int*   ql    = (const int*)d_in[0];
    const int*   color = (const int*)d_in[1];
    const float* qf    = (const float*)d_in[2];
    const float* sf    = (const float*)d_in[3];
    float* out = (float*)d_out;

    float* invq = (float*)d_ws;
    float* invs = invq + MTOT;
    int*   slot = (int*)(invs + MTOT);
    int*   cnt  = slot + MTOT;
    unsigned short* qbt = (unsigned short*)(cnt + 4);
    unsigned short* sbt = qbt + (size_t)MTOT * CDIM;
    float* part = (float*)(sbt + (size_t)MTOT * CDIM);

    hipMemsetAsync(cnt, 0, 16, stream);
    prep_kernel<<<MTOT / 256, 256, 0, stream>>>(ql, color, qf, sf, invq, invs, slot, cnt);
    convert_kernel<<<2 * (MTOT / 32), 256, 0, stream>>>(qf, sf, invq, invs, slot, qbt, sbt);
    matchsim_kernel<<<(MTOT / BN) * NCHUNK, 256, 0, stream>>>(qbt, sbt, cnt, part);
    finalize_kernel<<<MTOT / 256, 256, 0, stream>>>(part, out);
}

// Round 6
// 240.411 us; speedup vs baseline: 4.3420x; 1.0526x over previous
//
#include <hip/hip_runtime.h>
#include <math.h>

#define MTOT 9216      // 96*96 pixels
#define CDIM 256
#define KSEL 20
#define NCHUNK 8
#define CHUNKM 1152
#define BN 32          // rows (support pixels) per block
#define BM 128         // cols (query pixels) per tile
#define NTILES 9       // CHUNKM / BM

typedef __attribute__((ext_vector_type(8))) short short8;
typedef __attribute__((ext_vector_type(8))) unsigned short ushort8;
typedef __attribute__((ext_vector_type(4))) float f32x4;
typedef __attribute__((ext_vector_type(4))) unsigned int u32x4;
typedef __attribute__((ext_vector_type(2))) _Float16 h2;   // packed half pair

__device__ __forceinline__ unsigned short f2bf(float v) {
    unsigned u = __float_as_uint(v);
    u += 0x7FFF + ((u >> 16) & 1);          // RNE
    return (unsigned short)(u >> 16);
}
__device__ __forceinline__ unsigned int pkrtz(float lo, float hi) {
    auto r = __builtin_amdgcn_cvt_pkrtz(lo, hi);   // v_cvt_pkrtz_f16_f32 (__fp16 x2)
    unsigned int u; __builtin_memcpy(&u, &r, 4); return u;
}
__device__ __forceinline__ h2 asH2(unsigned int u) {
    h2 h; __builtin_memcpy(&h, &u, 4); return h;
}
__device__ __forceinline__ unsigned int h2u(h2 h) {
    unsigned int u; __builtin_memcpy(&u, &h, 4); return u;
}
__device__ __forceinline__ h2 h2max(h2 a, h2 b) { return __builtin_elementwise_max(a, b); }
__device__ __forceinline__ h2 h2min(h2 a, h2 b) { return __builtin_elementwise_min(a, b); }
__device__ __forceinline__ unsigned short hbits(_Float16 x) {
    unsigned short u; __builtin_memcpy(&u, &x, 2); return u;
}
__device__ __forceinline__ float hs2f(unsigned short u) {
    _Float16 x; __builtin_memcpy(&x, &u, 2); return (float)x;
}

// packed dual-list insert: lane .x = list A, lane .y = list B, independent.
// 39 v_pk ops insert one value into each half-list (clamped no-op if <= head).
__device__ __forceinline__ void ins20p(h2 (&l)[KSEL], h2 v) {
    v = h2max(v, l[0]);
#pragma unroll
    for (int i = 0; i < KSEL - 1; ++i) {
        h2 nxt = l[i + 1];
        l[i] = h2min(nxt, v);
        v = h2max(nxt, v);
    }
    l[KSEL - 1] = v;
}
// scalar f32 insert for finalize (caller guards v > l[0])
__device__ __forceinline__ void ins20(float (&l)[KSEL], float v) {
#pragma unroll
    for (int i = 0; i < KSEL - 1; ++i) {
        float nxt = l[i + 1];
        l[i] = fminf(nxt, v);
        v = fmaxf(nxt, v);
    }
    l[KSEL - 1] = v;
}

// Kernel 1 (fused prep+convert): one pass over f32 data -> norms, mask/slot,
// normalized bf16 transposed [m][C] (q permuted class-sorted by slot)
__global__ __launch_bounds__(256) void prepconv_kernel(
    const int* __restrict__ ql, const int* __restrict__ color,
    const float* __restrict__ qf, const float* __restrict__ sf,
    int* __restrict__ cnt,
    unsigned short* __restrict__ qbt, unsigned short* __restrict__ sbt)
{
    __shared__ float tilef[32 * 257];   // stride 257: conflict-free ph1 writes
    __shared__ float red[256];
    __shared__ float invv[32];
    __shared__ int slotl[32];
    const int bid = blockIdx.x;
    const bool isQ = bid < (MTOT / 32);
    const int m0 = (isQ ? bid : bid - MTOT / 32) * 32;
    const float* src = isQ ? qf : sf;
    const int t = threadIdx.x;
    const int ml = t & 31, cb = t >> 5;
    float sq = 0.f;
#pragma unroll
    for (int i = 0; i < 32; ++i) {
        int c = cb * 32 + i;
        float v = src[c * MTOT + m0 + ml];
        tilef[ml * 257 + c] = v;
        sq += v * v;
    }
    red[cb * 32 + ml] = sq;
    __syncthreads();
    if (t < 32) {
        float s = 0.f;
#pragma unroll
        for (int j = 0; j < 8; ++j) s += red[j * 32 + t];
        invv[t] = 1.0f / fmaxf(sqrtf(s), 1e-12f);
        if (isQ) {
            int m = m0 + t;
            bool fg = (ql[3*m] == color[0]) & (ql[3*m+1] == color[1]) & (ql[3*m+2] == color[2]);
            slotl[t] = fg ? atomicAdd(&cnt[0], 1) : (MTOT - 1 - atomicAdd(&cnt[1], 1));
        }
    }
    __syncthreads();
    const int row = t >> 3, seg = t & 7;
    const float iv = invv[row];
    const int drow = isQ ? slotl[row] : (m0 + row);
    unsigned short* dst = (isQ ? qbt : sbt) + (size_t)drow * 256 + seg * 32;
    const float* srcr = &tilef[row * 257 + seg * 32];
#pragma unroll
    for (int ch = 0; ch < 4; ++ch) {
        ushort8 o;
#pragma unroll
        for (int e = 0; e < 8; ++e) o[e] = f2bf(srcr[ch * 8 + e] * iv);
        *(ushort8*)(dst + ch * 8) = o;
    }
}

// Kernel 2: MFMA sim tiles + packed-f16 streaming top-20 (fg/bg) per chunk
__global__ __launch_bounds__(256, 4) void matchsim_kernel(
    const unsigned short* __restrict__ qbt, const unsigned short* __restrict__ sbt,
    const int* __restrict__ cnt, unsigned short* __restrict__ part)
{
    // Sb[32][256]bf16 swz @0 (16K) | Qb[128][64]bf16 swz @16K (16K) |
    // simt half2[16][128] @32K (8K) = 40960 B total -> 4 blocks/CU.
    // merge phase aliases all 40K: [2 cls][16 cg][16 rp][20] u32.
    __shared__ __align__(16) char smem[40960];
    char* Qb = smem + 16384;
    unsigned int* simt = (unsigned int*)(smem + 32768);
    unsigned int* mbuf = (unsigned int*)smem;

    const int t = threadIdx.x;
    const int w = t >> 6, l = t & 63;
    const int rowblk = blockIdx.x >> 3;
    const int chunk = blockIdx.x & 7;
    const int r0 = rowblk * BN;
    const int mbase = chunk * CHUNKM;
    const int fgc = cnt[0];

    // stage Sb: full K resident, swizzled rows (512 B each)
    {
        int row = t >> 3, cb = t & 7;
        const ushort8* gs = (const ushort8*)(sbt + (size_t)(r0 + row) * 256);
#pragma unroll
        for (int i = 0; i < 4; ++i) {
            int ch = cb + i * 8;
            ushort8 v = gs[ch];
            int byte = (row * 512 + ch * 16) ^ ((row & 7) << 4);
            *(ushort8*)(smem + byte) = v;
        }
    }

    const h2 NEG2 = { (_Float16)-65504.f, (_Float16)-65504.f };
    h2 fgl[KSEL], bgl[KSEL];
#pragma unroll
    for (int i = 0; i < KSEL; ++i) { fgl[i] = NEG2; bgl[i] = NEG2; }

    // Q register prefetch (64 B / thread / kc-slab)
    ushort8 qr[4];
    const int qml = t >> 3, qch = t & 7;
    auto loadQ = [&](int tt, int kk) {
        const unsigned short* base = qbt + (size_t)(mbase + tt * BM) * 256 + kk * 64 + qch * 8;
#pragma unroll
        for (int i = 0; i < 4; ++i)
            qr[i] = *(const ushort8*)(base + (size_t)(qml + 32 * i) * 256);
    };
    loadQ(0, 0);

    // fragment addressing (byte offsets + XOR swizzle)
    const int arow = l & 15;
    const int aswz = (arow & 7) << 4;
    const int abase0 = arow * 512;
    const int abase1 = (arow + 16) * 512;
    const int kofs = (l >> 4) * 16;
    const int bcol0 = w * 32 + (l & 15);
    const int bcol1 = bcol0 + 16;
    const int bbyte0 = bcol0 * 128, bswz0 = (bcol0 & 7) << 4;
    const int bbyte1 = bcol1 * 128, bswz1 = (bcol1 & 7) << 4;
    const int rbase = (l >> 4) * 4;
    const int c0 = w * 32 + (l & 15);
    const int selrp = t & 15, selcg = t >> 4;

    for (int tile = 0; tile < NTILES; ++tile) {
        f32x4 acc00 = {0,0,0,0}, acc01 = {0,0,0,0}, acc10 = {0,0,0,0}, acc11 = {0,0,0,0};
        for (int kcb = 0; kcb < 4; ++kcb) {
            // kcb==0 needs no barrier: the previous tile's sync-after-selection
            // already ordered all Qb readers before this overwrite.
            if (kcb) __syncthreads();
#pragma unroll
            for (int i = 0; i < 4; ++i) {           // write Qb slab
                int mlr = qml + 32 * i;
                int byte = (mlr * 128 + qch * 16) ^ ((mlr & 7) << 4);
                *(ushort8*)(Qb + byte) = qr[i];
            }
            int nk = kcb + 1, nt = tile;
            if (nk == 4) { nk = 0; ++nt; }
            if (nt < NTILES) loadQ(nt, nk);
            __syncthreads();
#pragma unroll
            for (int ks = 0; ks < 2; ++ks) {
                int kb = kcb * 128 + ks * 64 + kofs;
                short8 a0 = *(const short8*)(smem + ((abase0 + kb) ^ aswz));
                short8 a1 = *(const short8*)(smem + ((abase1 + kb) ^ aswz));
                int klb = ks * 64 + kofs;
                short8 b0 = *(const short8*)(Qb + ((bbyte0 + klb) ^ bswz0));
                short8 b1 = *(const short8*)(Qb + ((bbyte1 + klb) ^ bswz1));
                acc00 = __builtin_amdgcn_mfma_f32_16x16x32_bf16(a0, b0, acc00, 0, 0, 0);
                acc01 = __builtin_amdgcn_mfma_f32_16x16x32_bf16(a0, b1, acc01, 0, 0, 0);
                acc10 = __builtin_amdgcn_mfma_f32_16x16x32_bf16(a1, b0, acc10, 0, 0, 0);
                acc11 = __builtin_amdgcn_mfma_f32_16x16x32_bf16(a1, b1, acc11, 0, 0, 0);
            }
        }
        // epilogue: pack (row rr, rr+16) pairs -> simt half2[16][128]
#pragma unroll
        for (int r = 0; r < 4; ++r) {
            int rr = rbase + r;
            simt[rr * 128 + c0]      = pkrtz(acc00[r], acc10[r]);
            simt[rr * 128 + c0 + 16] = pkrtz(acc01[r], acc11[r]);
        }
        __syncthreads();
        // selection: thread owns row-pair (rp, rp+16) x 8 cols; packed inserts
        {
            const u32x4* sp = (const u32x4*)(simt + selrp * 128 + selcg * 8);
            u32x4 A = sp[0], B = sp[1];
            h2 v0 = asH2(A.x), v1 = asH2(A.y), v2 = asH2(A.z), v3 = asH2(A.w);
            h2 v4 = asH2(B.x), v5 = asH2(B.y), v6 = asH2(B.z), v7 = asH2(B.w);
            int mcol = mbase + tile * BM + selcg * 8;
            if (mcol + 8 <= fgc) {
                ins20p(fgl, v0); ins20p(fgl, v1); ins20p(fgl, v2); ins20p(fgl, v3);
                ins20p(fgl, v4); ins20p(fgl, v5); ins20p(fgl, v6); ins20p(fgl, v7);
            } else if (mcol >= fgc) {
                ins20p(bgl, v0); ins20p(bgl, v1); ins20p(bgl, v2); ins20p(bgl, v3);
                ins20p(bgl, v4); ins20p(bgl, v5); ins20p(bgl, v6); ins20p(bgl, v7);
            } else {        // boundary group: masked into both (rare)
                h2 vs[8] = {v0,v1,v2,v3,v4,v5,v6,v7};
#pragma unroll
                for (int c = 0; c < 8; ++c) {
                    bool m = (mcol + c) < fgc;
                    ins20p(fgl, m ? vs[c] : NEG2);
                    ins20p(bgl, m ? NEG2 : vs[c]);
                }
            }
        }
        __syncthreads();   // selection done before next tile's Qb/simt rewrites
    }

    // dump packed lists: mbuf[cls][cg][rp][20]
    {
        unsigned int* df = &mbuf[((0  + selcg) * 16 + selrp) * KSEL];
        unsigned int* db = &mbuf[((16 + selcg) * 16 + selrp) * KSEL];
#pragma unroll
        for (int k = 0; k < KSEL; ++k) { df[k] = h2u(fgl[k]); db[k] = h2u(bgl[k]); }
    }
    __syncthreads();
    // merge tree over cg: 16 -> 8 -> 4 -> 2 -> 1 (packed guarded inserts)
    auto mergeL = [&](unsigned int* A, const unsigned int* B) {
        h2 la[KSEL];
#pragma unroll
        for (int k = 0; k < KSEL; ++k) la[k] = asH2(A[k]);
        for (int j = KSEL - 1; j >= 0; --j) {
            h2 v = asH2(B[j]);
            if (!(v.x > la[0].x || v.y > la[0].y)) break;
            ins20p(la, v);
        }
#pragma unroll
        for (int k = 0; k < KSEL; ++k) A[k] = h2u(la[k]);
    };
    {   // level 1: all 256 threads
        int cls = t >> 7, u = t & 127, rp = u & 15, j = u >> 4;
        mergeL(&mbuf[((cls*16 + 2*j)*16 + rp)*KSEL], &mbuf[((cls*16 + 2*j+1)*16 + rp)*KSEL]);
    }
    __syncthreads();
    if (t < 128) {
        int cls = t >> 6, u = t & 63, rp = u & 15, j = u >> 4;
        mergeL(&mbuf[((cls*16 + 4*j)*16 + rp)*KSEL], &mbuf[((cls*16 + 4*j+2)*16 + rp)*KSEL]);
    }
    __syncthreads();
    if (t < 64) {
        int cls = t >> 5, u = t & 31, rp = u & 15, j = u >> 4;
        mergeL(&mbuf[((cls*16 + 8*j)*16 + rp)*KSEL], &mbuf[((cls*16 + 8*j+4)*16 + rp)*KSEL]);
    }
    __syncthreads();
    if (t < 32) {   // final level in registers + part write (f16 lists)
        int cls = t >> 4, rp = t & 15;
        unsigned int* A = &mbuf[((cls*16 + 0)*16 + rp)*KSEL];
        const unsigned int* B = &mbuf[((cls*16 + 8)*16 + rp)*KSEL];
        h2 la[KSEL];
#pragma unroll
        for (int k = 0; k < KSEL; ++k) la[k] = asH2(A[k]);
        for (int j = KSEL - 1; j >= 0; --j) {
            h2 v = asH2(B[j]);
            if (!(v.x > la[0].x || v.y > la[0].y)) break;
            ins20p(la, v);
        }
        unsigned short* d0 = &part[((size_t)(r0 + rp)      * NCHUNK + chunk) * (2*KSEL) + cls*KSEL];
        unsigned short* d1 = &part[((size_t)(r0 + rp + 16) * NCHUNK + chunk) * (2*KSEL) + cls*KSEL];
#pragma unroll
        for (int k = 0; k < KSEL; ++k) {
            d0[k] = hbits(la[k].x);
            d1[k] = hbits(la[k].y);
        }
    }
}

// Kernel 3: merge 8 chunk-lists per row per class -> mean (f32)
__global__ __launch_bounds__(256) void finalize_kernel(
    const unsigned short* __restrict__ part, float* __restrict__ out)
{
    int n = blockIdx.x * 256 + threadIdx.x;
    if (n >= MTOT) return;
    const unsigned short* base = part + (size_t)n * NCHUNK * 2 * KSEL;
#pragma unroll
    for (int cls = 0; cls < 2; ++cls) {
        float la[KSEL];
        const unsigned short* c0p = base + cls * KSEL;
#pragma unroll
        for (int k = 0; k < KSEL; ++k) la[k] = hs2f(c0p[k]);
        for (int ch = 1; ch < NCHUNK; ++ch) {
            const unsigned short* sp = base + ch * 2 * KSEL + cls * KSEL;
            for (int j = KSEL - 1; j >= 0; --j) {
                float v = hs2f(sp[j]);
                if (v <= la[0]) break;
                ins20(la, v);
            }
        }
        float s = 0.f;
#pragma unroll
        for (int k = 0; k < KSEL; ++k) s += la[k];
        out[cls * MTOT + n] = s * (1.0f / KSEL);
    }
}

extern "C" void kernel_launch(void* const* d_in, const int* in_sizes, int n_in,
                              void* d_out, int out_size, void* d_ws, size_t ws_size,
                              hipStream_t stream) {
    const int*   ql    = (const int*)d_in[0];
    const int*   color = (const int*)d_in[1];
    const float* qf    = (const float*)d_in[2];
    const float* sf    = (const float*)d_in[3];
    float* out = (float*)d_out;

    // ws: cnt[4] i32 | qbt bf16[9216*256] | sbt bf16[9216*256] | part u16[9216*8*40]
    int* cnt = (int*)d_ws;
    unsigned short* qbt = (unsigned short*)(cnt + 4);
    unsigned short* sbt = qbt + (size_t)MTOT * CDIM;
    unsigned short* part = sbt + (size_t)MTOT * CDIM;

    (void)hipMemsetAsync(cnt, 0, 16, stream);
    prepconv_kernel<<<2 * (MTOT / 32), 256, 0, stream>>>(ql, color, qf, sf, cnt, qbt, sbt);
    matchsim_kernel<<<(MTOT / BN) * NCHUNK, 256, 0, stream>>>(qbt, sbt, cnt, part);
    finalize_kernel<<<MTOT / 256, 256, 0, stream>>>(part, out);
}

// Round 7
// 212.627 us; speedup vs baseline: 4.9094x; 1.1307x over previous
//
#include <hip/hip_runtime.h>
#include <math.h>

#define MTOT 9216      // 96*96 pixels
#define CDIM 256
#define KSEL 20
#define NCHUNK 4
#define CHUNKQ 2304    // q pixels per chunk
#define BS 32          // s pixels per block (resident)
#define QSTEP 128      // q per step (4 waves x 2 qtiles x 16)
#define NSTEP 18       // CHUNKQ / QSTEP
#define NSLAB 72       // NSTEP * 4 k-slabs of 64

typedef __attribute__((ext_vector_type(8))) short short8;
typedef __attribute__((ext_vector_type(8))) unsigned short ushort8;
typedef __attribute__((ext_vector_type(4))) float f32x4;
typedef __attribute__((ext_vector_type(2))) _Float16 h2;

__device__ __forceinline__ unsigned short f2bf(float v) {
    unsigned u = __float_as_uint(v);
    u += 0x7FFF + ((u >> 16) & 1);          // RNE
    return (unsigned short)(u >> 16);
}
__device__ __forceinline__ h2 pkh2(float lo, float hi) {
    auto r = __builtin_amdgcn_cvt_pkrtz(lo, hi);   // v_cvt_pkrtz_f16_f32
    h2 h; __builtin_memcpy(&h, &r, 4); return h;
}
__device__ __forceinline__ h2 asH2(unsigned int u) {
    h2 h; __builtin_memcpy(&h, &u, 4); return h;
}
__device__ __forceinline__ unsigned int h2u(h2 h) {
    unsigned int u; __builtin_memcpy(&u, &h, 4); return u;
}
__device__ __forceinline__ h2 h2max(h2 a, h2 b) { return __builtin_elementwise_max(a, b); }
__device__ __forceinline__ h2 h2min(h2 a, h2 b) { return __builtin_elementwise_min(a, b); }
__device__ __forceinline__ unsigned short hbits(_Float16 x) {
    unsigned short u; __builtin_memcpy(&u, &x, 2); return u;
}
__device__ __forceinline__ float hs2f(unsigned short u) {
    _Float16 x; __builtin_memcpy(&x, &u, 2); return (float)x;
}

// packed dual-list insert (lists independent per half); clamped no-op if <= head
__device__ __forceinline__ void ins20p(h2 (&l)[KSEL], h2 v) {
    v = h2max(v, l[0]);
#pragma unroll
    for (int i = 0; i < KSEL - 1; ++i) {
        h2 nxt = l[i + 1];
        l[i] = h2min(nxt, v);
        v = h2max(nxt, v);
    }
    l[KSEL - 1] = v;
}
__device__ __forceinline__ void ins20(float (&l)[KSEL], float v) {
#pragma unroll
    for (int i = 0; i < KSEL - 1; ++i) {
        float nxt = l[i + 1];
        l[i] = fminf(nxt, v);
        v = fmaxf(nxt, v);
    }
    l[KSEL - 1] = v;
}

// Kernel 1: fused norms + mask/slot + normalized bf16 transpose [m][C]
__global__ __launch_bounds__(256) void prepconv_kernel(
    const int* __restrict__ ql, const int* __restrict__ color,
    const float* __restrict__ qf, const float* __restrict__ sf,
    int* __restrict__ cnt,
    unsigned short* __restrict__ qbt, unsigned short* __restrict__ sbt)
{
    __shared__ float tilef[32 * 257];
    __shared__ float red[256];
    __shared__ float invv[32];
    __shared__ int slotl[32];
    const int bid = blockIdx.x;
    const bool isQ = bid < (MTOT / 32);
    const int m0 = (isQ ? bid : bid - MTOT / 32) * 32;
    const float* src = isQ ? qf : sf;
    const int t = threadIdx.x;
    const int ml = t & 31, cb = t >> 5;
    float sq = 0.f;
#pragma unroll
    for (int i = 0; i < 32; ++i) {
        int c = cb * 32 + i;
        float v = src[c * MTOT + m0 + ml];
        tilef[ml * 257 + c] = v;
        sq += v * v;
    }
    red[cb * 32 + ml] = sq;
    __syncthreads();
    if (t < 32) {
        float s = 0.f;
#pragma unroll
        for (int j = 0; j < 8; ++j) s += red[j * 32 + t];
        invv[t] = 1.0f / fmaxf(sqrtf(s), 1e-12f);
        if (isQ) {
            int m = m0 + t;
            bool fg = (ql[3*m] == color[0]) & (ql[3*m+1] == color[1]) & (ql[3*m+2] == color[2]);
            slotl[t] = fg ? atomicAdd(&cnt[0], 1) : (MTOT - 1 - atomicAdd(&cnt[1], 1));
        }
    }
    __syncthreads();
    const int row = t >> 3, seg = t & 7;
    const float iv = invv[row];
    const int drow = isQ ? slotl[row] : (m0 + row);
    unsigned short* dst = (isQ ? qbt : sbt) + (size_t)drow * 256 + seg * 32;
    const float* srcr = &tilef[row * 257 + seg * 32];
#pragma unroll
    for (int ch = 0; ch < 4; ++ch) {
        ushort8 o;
#pragma unroll
        for (int e = 0; e < 8; ++e) o[e] = f2bf(srcr[ch * 8 + e] * iv);
        *(ushort8*)(dst + ch * 8) = o;
    }
}

// Kernel 2: swapped-operand MFMA C[q][s]; selection straight from acc regs.
__global__ __launch_bounds__(256, 3) void matchsim_kernel(
    const unsigned short* __restrict__ qbt, const unsigned short* __restrict__ sbt,
    const int* __restrict__ cnt, unsigned short* __restrict__ part)
{
    // Sb[32][256] swz @0 (16K) | Qs[2][128][64] swz @16K,@32K (16K each) = 48K.
    // merge alias @0: u32 [2 cls][16 owner][16 sp] stride 21 -> 43008 B.
    __shared__ __align__(16) char smem[49152];
    unsigned int* mbuf = (unsigned int*)smem;

    const int t = threadIdx.x;
    const int w = t >> 6, l = t & 63;
    const int sblk = blockIdx.x >> 2;
    const int chunk = blockIdx.x & 3;
    const int s0 = sblk * BS;
    const int q0c = chunk * CHUNKQ;
    const int fgc = cnt[0];

    // stage Sb: 32 s-rows x 512 B, XOR-swizzled
    {
        int row = t >> 3, cb = t & 7;
        const ushort8* gs = (const ushort8*)(sbt + (size_t)(s0 + row) * 256);
#pragma unroll
        for (int i = 0; i < 4; ++i) {
            int ch = cb + i * 8;
            ushort8 v = gs[ch];
            int byte = (row * 512 + ch * 16) ^ ((row & 7) << 4);
            *(ushort8*)(smem + byte) = v;
        }
    }

    const h2 NEG2 = { (_Float16)-65504.f, (_Float16)-65504.f };
    h2 fgl[KSEL], bgl[KSEL];
#pragma unroll
    for (int i = 0; i < KSEL; ++i) { fgl[i] = NEG2; bgl[i] = NEG2; }

    // Q slab prefetch: 4 x 16B per thread per slab (row = t>>1, half = t&1)
    ushort8 qr[4];
    const int qrow_w = t >> 1, qhalf = t & 1;
    auto loadQ = [&](int gslab) {
        int step = gslab >> 2, slab = gslab & 3;
        const unsigned short* base =
            qbt + (size_t)(q0c + step * QSTEP + qrow_w) * 256 + slab * 64 + qhalf * 32;
#pragma unroll
        for (int i = 0; i < 4; ++i)
            qr[i] = *(const ushort8*)(base + i * 8);
    };
    loadQ(0);
    const int qwswz = (qrow_w & 7) << 4;

    // fragment addressing
    const int lg = l >> 4;                        // lane k-group
    const int aq0 = w * 32 + (l & 15);            // qtile0 row in Qs
    const int aq1 = aq0 + 16;
    const int aswz0 = (aq0 & 7) << 4, aswz1 = (aq1 & 7) << 4;
    const int srow0 = l & 15, srow1 = srow0 + 16; // stile rows in Sb
    const int bswz0 = (srow0 & 7) << 4, bswz1 = (srow1 & 7) << 4;

    f32x4 acc00 = {0,0,0,0}, acc01 = {0,0,0,0}, acc10 = {0,0,0,0}, acc11 = {0,0,0,0};
    int cur = 0;

    for (int gslab = 0; gslab < NSLAB; ++gslab) {
        char* Qs = smem + 16384 + cur * 16384;
        // write prefetched slab -> LDS (swizzled)
#pragma unroll
        for (int i = 0; i < 4; ++i) {
            int byte = (qrow_w * 128 + qhalf * 64 + i * 16) ^ qwswz;
            *(ushort8*)(Qs + byte) = qr[i];
        }
        if (gslab + 1 < NSLAB) loadQ(gslab + 1);
        // Single barrier per slab is safe: writes of slab i+1 target buf (i+1)&1
        // while MFMA of slab i reads buf i&1; writes of slab i+2 (same buf as i)
        // can only start after barrier i+1, which all waves reach only after
        // completing MFMA i (program order).
        __syncthreads();
        const int slab = gslab & 3;
#pragma unroll
        for (int ks = 0; ks < 2; ++ks) {
            int ak = ks * 64 + lg * 16;
            short8 a0 = *(const short8*)(Qs + ((aq0 * 128 + ak) ^ aswz0));
            short8 a1 = *(const short8*)(Qs + ((aq1 * 128 + ak) ^ aswz1));
            int bk = slab * 128 + ks * 64 + lg * 16;
            short8 b0 = *(const short8*)(smem + ((srow0 * 512 + bk) ^ bswz0));
            short8 b1 = *(const short8*)(smem + ((srow1 * 512 + bk) ^ bswz1));
            acc00 = __builtin_amdgcn_mfma_f32_16x16x32_bf16(a0, b0, acc00, 0, 0, 0);
            acc01 = __builtin_amdgcn_mfma_f32_16x16x32_bf16(a0, b1, acc01, 0, 0, 0);
            acc10 = __builtin_amdgcn_mfma_f32_16x16x32_bf16(a1, b0, acc10, 0, 0, 0);
            acc11 = __builtin_amdgcn_mfma_f32_16x16x32_bf16(a1, b1, acc11, 0, 0, 0);
        }
        cur ^= 1;
        if (slab == 3) {
            // selection from registers: pair (s0+sp, s0+16+sp) per value
            const int step = gslab >> 2;
            const int qw0 = q0c + step * QSTEP + w * 32;
#pragma unroll
            for (int qt = 0; qt < 2; ++qt) {
                const f32x4& aS0 = qt ? acc10 : acc00;
                const f32x4& aS1 = qt ? acc11 : acc01;
                int qfirst = qw0 + qt * 16;
                if (qfirst + 16 <= fgc) {
#pragma unroll
                    for (int r = 0; r < 4; ++r) ins20p(fgl, pkh2(aS0[r], aS1[r]));
                } else if (qfirst >= fgc) {
#pragma unroll
                    for (int r = 0; r < 4; ++r) ins20p(bgl, pkh2(aS0[r], aS1[r]));
                } else {    // boundary 16-q window (rare)
#pragma unroll
                    for (int r = 0; r < 4; ++r) {
                        h2 v = pkh2(aS0[r], aS1[r]);
                        bool m = (qfirst + lg * 4 + r) < fgc;
                        ins20p(fgl, m ? v : NEG2);
                        ins20p(bgl, m ? NEG2 : v);
                    }
                }
            }
            acc00 = (f32x4){0,0,0,0}; acc01 = (f32x4){0,0,0,0};
            acc10 = (f32x4){0,0,0,0}; acc11 = (f32x4){0,0,0,0};
        }
    }

    __syncthreads();   // all MFMA done before mbuf aliases Sb/Qs
    // dump: mbuf[(cls*16 + owner)*16*21 ... ] layout (cls, owner, sp) stride 21
    const int sp = l & 15, owner = w * 4 + lg;
    auto midx = [](int cls, int own, int spi) { return ((cls * 16 + own) * 16 + spi) * 21; };
    {
        unsigned int* df = &mbuf[midx(0, owner, sp)];
        unsigned int* db = &mbuf[midx(1, owner, sp)];
#pragma unroll
        for (int k = 0; k < KSEL; ++k) { df[k] = h2u(fgl[k]); db[k] = h2u(bgl[k]); }
    }
    __syncthreads();
    auto mergeL = [&](unsigned int* A, const unsigned int* B) {
        h2 la[KSEL];
#pragma unroll
        for (int k = 0; k < KSEL; ++k) la[k] = asH2(A[k]);
        for (int j = KSEL - 1; j >= 0; --j) {
            h2 v = asH2(B[j]);
            if (!(v.x > la[0].x || v.y > la[0].y)) break;
            ins20p(la, v);
        }
#pragma unroll
        for (int k = 0; k < KSEL; ++k) A[k] = h2u(la[k]);
    };
    {   // 16 -> 8 owners
        int cls = t >> 7, u = t & 127, spi = u & 15, j = u >> 4;
        mergeL(&mbuf[midx(cls, j, spi)], &mbuf[midx(cls, j + 8, spi)]);
    }
    __syncthreads();
    if (t < 128) {
        int cls = t >> 6, u = t & 63, spi = u & 15, j = u >> 4;
        mergeL(&mbuf[midx(cls, j, spi)], &mbuf[midx(cls, j + 4, spi)]);
    }
    __syncthreads();
    if (t < 64) {
        int cls = t >> 5, u = t & 31, spi = u & 15, j = u >> 4;
        mergeL(&mbuf[midx(cls, j, spi)], &mbuf[midx(cls, j + 2, spi)]);
    }
    __syncthreads();
    if (t < 32) {   // final merge + part write (.x -> s0+sp, .y -> s0+16+sp)
        int cls = t >> 4, spi = t & 15;
        unsigned int* A = &mbuf[midx(cls, 0, spi)];
        const unsigned int* B = &mbuf[midx(cls, 1, spi)];
        h2 la[KSEL];
#pragma unroll
        for (int k = 0; k < KSEL; ++k) la[k] = asH2(A[k]);
        for (int j = KSEL - 1; j >= 0; --j) {
            h2 v = asH2(B[j]);
            if (!(v.x > la[0].x || v.y > la[0].y)) break;
            ins20p(la, v);
        }
        unsigned short* d0 = &part[((size_t)(s0 + spi)      * NCHUNK + chunk) * (2*KSEL) + cls*KSEL];
        unsigned short* d1 = &part[((size_t)(s0 + 16 + spi) * NCHUNK + chunk) * (2*KSEL) + cls*KSEL];
#pragma unroll
        for (int k = 0; k < KSEL; ++k) {
            d0[k] = hbits(la[k].x);
            d1[k] = hbits(la[k].y);
        }
    }
}

// Kernel 3: merge NCHUNK chunk-lists per row per class -> mean (f32)
__global__ __launch_bounds__(256) void finalize_kernel(
    const unsigned short* __restrict__ part, float* __restrict__ out)
{
    int n = blockIdx.x * 256 + threadIdx.x;
    if (n >= MTOT) return;
    const unsigned short* base = part + (size_t)n * NCHUNK * 2 * KSEL;
#pragma unroll
    for (int cls = 0; cls < 2; ++cls) {
        float la[KSEL];
        const unsigned short* c0p = base + cls * KSEL;
#pragma unroll
        for (int k = 0; k < KSEL; ++k) la[k] = hs2f(c0p[k]);
        for (int ch = 1; ch < NCHUNK; ++ch) {
            const unsigned short* sp = base + ch * 2 * KSEL + cls * KSEL;
            for (int j = KSEL - 1; j >= 0; --j) {
                float v = hs2f(sp[j]);
                if (v <= la[0]) break;
                ins20(la, v);
            }
        }
        float s = 0.f;
#pragma unroll
        for (int k = 0; k < KSEL; ++k) s += la[k];
        out[cls * MTOT + n] = s * (1.0f / KSEL);
    }
}

extern "C" void kernel_launch(void* const* d_in, const int* in_sizes, int n_in,
                              void* d_out, int out_size, void* d_ws, size_t ws_size,
                              hipStream_t stream) {
    const int*   ql    = (const int*)d_in[0];
    const int*   color = (const int*)d_in[1];
    const float* qf    = (const float*)d_in[2];
    const float* sf    = (const float*)d_in[3];
    float* out = (float*)d_out;

    // ws: cnt[4] | qbt bf16[9216*256] | sbt bf16[9216*256] | part u16[9216*4*40]
    int* cnt = (int*)d_ws;
    unsigned short* qbt = (unsigned short*)(cnt + 4);
    unsigned short* sbt = qbt + (size_t)MTOT * CDIM;
    unsigned short* part = sbt + (size_t)MTOT * CDIM;

    (void)hipMemsetAsync(cnt, 0, 16, stream);
    prepconv_kernel<<<2 * (MTOT / 32), 256, 0, stream>>>(ql, color, qf, sf, cnt, qbt, sbt);
    matchsim_kernel<<<(MTOT / BS) * NCHUNK, 256, 0, stream>>>(qbt, sbt, cnt, part);
    finalize_kernel<<<MTOT / 256, 256, 0, stream>>>(part, out);
}